// Round 13
// baseline (574.464 us; speedup 1.0000x reference)
//
#include <hip/hip_runtime.h>
#include <hip/hip_fp16.h>

#define B_    64
#define V1_   4096
#define V2_   1024
#define DF_   8
#define K_    25
#define NP_   13
#define F1_   32
#define F2_   64
#define FC1F_ 512
#define FC2F_ 10
#define E1_   65536
#define E2_   16384
#define C1_   512
#define C2_   2048
#define FCIN_ 16384

typedef short bf16x8 __attribute__((ext_vector_type(8)));
typedef float f32x4  __attribute__((ext_vector_type(4)));
typedef unsigned u32x2 __attribute__((ext_vector_type(2)));
typedef unsigned u32x4 __attribute__((ext_vector_type(4)));

// acc += f16(hi16 of q) * f16(lo16 of g)   [f32 accumulate]
#define FMA_MIX_LO(acc, qv, gv) \
    asm("v_fma_mix_f32 %0, %1, %2, %0 op_sel:[1,0,0] op_sel_hi:[1,1,0]" \
        : "+v"(acc) : "v"(qv), "v"(gv))
// acc += f16(hi16 of q) * f16(hi16 of g)
#define FMA_MIX_HI(acc, qv, gv) \
    asm("v_fma_mix_f32 %0, %1, %2, %0 op_sel:[1,1,0] op_sel_hi:[1,1,0]" \
        : "+v"(acc) : "v"(qv), "v"(gv))

__device__ __forceinline__ unsigned short f2bf(float x) {
    unsigned u = __float_as_uint(x);
    u += 0x7FFFu + ((u >> 16) & 1u);
    return (unsigned short)(u >> 16);
}
__device__ __forceinline__ float h2f_lo(unsigned u) {
    return __half2float(__ushort_as_half((unsigned short)(u & 0xFFFFu)));
}
__device__ __forceinline__ float h2f_hi(unsigned u) {
    return __half2float(__ushort_as_half((unsigned short)(u >> 16)));
}

// ---------- input transpose: x[b,v,fin] -> XP[v][c=fin*64+b] f16 ----------
__global__ __launch_bounds__(256) void k_transpose_rm(const float* __restrict__ x,
                                                      unsigned* __restrict__ XP) {
    __shared__ float tsh[DF_][B_][16];
    const int t = threadIdx.x;
    const int v0 = blockIdx.x * 16;
    for (int rep = 0; rep < 4; ++rep) {
        int idx = rep*256 + t;
        int b = idx >> 4, vv = idx & 15;
        const float4* p = (const float4*)&x[((size_t)b*V1_ + v0 + vv)*DF_];
        float4 a0 = p[0], a1 = p[1];
        tsh[0][b][vv]=a0.x; tsh[1][b][vv]=a0.y; tsh[2][b][vv]=a0.z; tsh[3][b][vv]=a0.w;
        tsh[4][b][vv]=a1.x; tsh[5][b][vv]=a1.y; tsh[6][b][vv]=a1.z; tsh[7][b][vv]=a1.w;
    }
    __syncthreads();
    for (int rep = 0; rep < 16; ++rep) {
        int idx = rep*256 + t;
        int c2 = idx & 255, vv = idx >> 8;
        int c = c2*2, fin = c >> 6, b = c & 63;
        __half2 hh = __floats2half2_rn(tsh[fin][b][vv], tsh[fin][b+1][vv]);
        __builtin_nontemporal_store(*(const unsigned*)&hh,
                                    &XP[(size_t)(v0+vv)*256 + c2]);
    }
}

// ---------- CSR build (padded to 4-edge alignment, packed 4B edges) ----------
__global__ __launch_bounds__(256) void k_count(const int* __restrict__ rows, int E,
                                               int* __restrict__ cnt) {
    int e = blockIdx.x*256 + threadIdx.x;
    if (e < E) atomicAdd(&cnt[rows[e]], 1);
}

__global__ __launch_bounds__(256) void k_scan(const int* __restrict__ cnt, int V,
                                              int* __restrict__ offs, int* __restrict__ cursor) {
    __shared__ int psum[256];
    int t = threadIdx.x;
    int chunk = V >> 8;
    int lo = t*chunk;
    int s = 0;
    for (int i = lo; i < lo+chunk; ++i) s += (cnt[i] + 3) & ~3;
    psum[t] = s;
    __syncthreads();
    for (int off = 1; off < 256; off <<= 1) {
        int val = (t >= off) ? psum[t-off] : 0;
        __syncthreads();
        psum[t] += val;
        __syncthreads();
    }
    int run = (t == 0) ? 0 : psum[t-1];
    for (int i = lo; i < lo+chunk; ++i) {
        offs[i] = run; cursor[i] = run;
        run += (cnt[i] + 3) & ~3;
    }
    if (t == 255) offs[V] = run;
}

// edge payload: {f16 weight hi16, (col<<shift) lo16}
__global__ __launch_bounds__(256) void k_scatter(const int* __restrict__ rows,
                                                 const int* __restrict__ cols,
                                                 const float* __restrict__ vals, int E,
                                                 int shift,
                                                 int* __restrict__ cursor,
                                                 unsigned* __restrict__ ep) {
    int e = blockIdx.x*256 + threadIdx.x;
    if (e < E) {
        int p = atomicAdd(&cursor[rows[e]], 1);
        unsigned hv = (unsigned)__half_as_ushort(__float2half(vals[e]));
        ep[p] = (hv << 16) | ((unsigned)cols[e] << shift);
    }
}

// ---------- layer-1 dual Chebyshev step: 2 waves per row (256-col halves) ----------
// ppstk u32 pair-planes [p][v][c]: (bf16 x_{2p}) | (bf16 x_{2p+1})<<16 ; written at odd k
__global__ __launch_bounds__(1024, 8) void k_dcheb1(int k,
        const unsigned short* __restrict__ Xsrc,
        unsigned short* __restrict__ Xown,
        unsigned* __restrict__ ppstk,
        const int* __restrict__ offs,
        const unsigned* __restrict__ ep) {
    const int t = threadIdx.x;
    const int lane = t & 63;
    const int v = blockIdx.x*8 + (t >> 7);   // 16 waves, 2 per row
    const int h = (t >> 6) & 1;              // column half
    const int e0 = offs[v], e1 = offs[v+1];
    const unsigned coff = (unsigned)h*512u + (unsigned)lane*8u;   // byte offset in 1KB row
    float acc[4] = {0.f, 0.f, 0.f, 0.f};
    const char* srcb = (const char*)Xsrc;

    for (int e = e0; e < e1; e += 4) {
        const uint4 q = *(const uint4*)&ep[e];
        const uint2 g0 = *(const uint2*)(srcb + ((q.x & 0xFFFFu)*1024u + coff));
        const uint2 g1 = *(const uint2*)(srcb + ((q.y & 0xFFFFu)*1024u + coff));
        const uint2 g2 = *(const uint2*)(srcb + ((q.z & 0xFFFFu)*1024u + coff));
        const uint2 g3 = *(const uint2*)(srcb + ((q.w & 0xFFFFu)*1024u + coff));
        FMA_MIX_LO(acc[0], q.x, g0.x); FMA_MIX_HI(acc[1], q.x, g0.x);
        FMA_MIX_LO(acc[2], q.x, g0.y); FMA_MIX_HI(acc[3], q.x, g0.y);
        FMA_MIX_LO(acc[0], q.y, g1.x); FMA_MIX_HI(acc[1], q.y, g1.x);
        FMA_MIX_LO(acc[2], q.y, g1.y); FMA_MIX_HI(acc[3], q.y, g1.y);
        FMA_MIX_LO(acc[0], q.z, g2.x); FMA_MIX_HI(acc[1], q.z, g2.x);
        FMA_MIX_LO(acc[2], q.z, g2.y); FMA_MIX_HI(acc[3], q.z, g2.y);
        FMA_MIX_LO(acc[0], q.w, g3.x); FMA_MIX_HI(acc[1], q.w, g3.x);
        FMA_MIX_LO(acc[2], q.w, g3.y); FMA_MIX_HI(acc[3], q.w, g3.y);
    }

    float xn[4];
    if (k > 1) {
        const uint2 old = *(const uint2*)((const char*)Xown + ((size_t)v*1024 + coff));
        xn[0] = fmaf(2.f, acc[0], -h2f_lo(old.x));
        xn[1] = fmaf(2.f, acc[1], -h2f_hi(old.x));
        xn[2] = fmaf(2.f, acc[2], -h2f_lo(old.y));
        xn[3] = fmaf(2.f, acc[3], -h2f_hi(old.y));
    } else {
#pragma unroll
        for (int j = 0; j < 4; ++j) xn[j] = acc[j];
    }

    {   // new f16 state (nt: no reuse within this step)
        __half2 ha = __floats2half2_rn(xn[0], xn[1]);
        __half2 hb = __floats2half2_rn(xn[2], xn[3]);
        u32x2 hp = { *(const unsigned*)&ha, *(const unsigned*)&hb };
        __builtin_nontemporal_store(hp,
            (u32x2*)((char*)Xown + ((size_t)v*1024 + coff)));
    }

    if (k & 1) {                              // flush pair plane (x_{k-1}, x_k)
        const uint2 own = *(const uint2*)(srcb + ((size_t)v*1024 + coff));  // x_{k-1}
        const int p = k >> 1;
        u32x4 pr;
        pr.x = (unsigned)f2bf(h2f_lo(own.x)) | ((unsigned)f2bf(xn[0]) << 16);
        pr.y = (unsigned)f2bf(h2f_hi(own.x)) | ((unsigned)f2bf(xn[1]) << 16);
        pr.z = (unsigned)f2bf(h2f_lo(own.y)) | ((unsigned)f2bf(xn[2]) << 16);
        pr.w = (unsigned)f2bf(h2f_hi(own.y)) | ((unsigned)f2bf(xn[3]) << 16);
        __builtin_nontemporal_store(pr,
            (u32x4*)&ppstk[((size_t)p*V1_ + v)*512 + h*256 + lane*4]);
    } else if (k == 24) {                     // plane 12 = (x24, 0)
        u32x4 pr;
        pr.x = f2bf(xn[0]); pr.y = f2bf(xn[1]);
        pr.z = f2bf(xn[2]); pr.w = f2bf(xn[3]);
        __builtin_nontemporal_store(pr,
            (u32x4*)&ppstk[((size_t)12*V1_ + v)*512 + h*256 + lane*4]);
    }
}

// ---------- W prep (conv): Wb[fin][g][f][kk] = bf16(W[f][fin*25+g*8+kk]), 0-padded ----------
template<int FIN, int F>
__global__ __launch_bounds__(256) void k_wprep(const float* __restrict__ W,
                                               unsigned short* __restrict__ Wb) {
    int idx = blockIdx.x*256 + threadIdx.x;
    int kk  = idx & 7;
    int f   = (idx >> 3) % F;
    int g   = (idx >> 3) / F % 4;
    int fin = idx / (8*F*4);
    int k = g*8 + kk;
    Wb[idx] = (k < K_) ? f2bf(W[(size_t)f*(FIN*K_) + fin*K_ + k]) : 0;
}

// ---------- W prep (fc1): f32 -> bf16 flat copy ----------
__global__ __launch_bounds__(256) void k_wprep_fc(const float* __restrict__ W,
                                                  unsigned short* __restrict__ Wb) {
    int idx = (blockIdx.x*256 + threadIdx.x)*4;
    float4 w = *(const float4*)&W[idx];
    ushort4 o;
    o.x = f2bf(w.x); o.y = f2bf(w.y); o.z = f2bf(w.z); o.w = f2bf(w.w);
    *(ushort4*)&Wb[idx] = o;
}

// ---------- layer-1 MFMA GEMM (pair-planes [p][v][c]) + relu + pool -> X0T2 ----------
__global__ __launch_bounds__(256) void k_gemm1c(const unsigned* __restrict__ pp,
                                                const unsigned short* __restrict__ Wb,
                                                const float* __restrict__ bias,
                                                float* __restrict__ X0T2) {
    const int t = threadIdx.x, lane = t & 63, wave = t >> 6;
    const int v2 = blockIdx.x*4 + wave;
    const int m = lane & 15, g = lane >> 4;
    size_t pbase[4];
#pragma unroll
    for (int p = 0; p < 4; ++p) {
        int pq = g*4 + p; if (pq > 12) pq = 12;   // k>=26 -> plane12, Wb=0 kills it
        pbase[p] = (size_t)pq * V1_ * 512;
    }
    float bv[2] = { bias[m], bias[16+m] };
    f32x4 pool[4][2];

    for (int vv = 0; vv < 4; ++vv) {
        const int v = v2*4 + vv;
        f32x4 acc[4][2];
#pragma unroll
        for (int mt = 0; mt < 4; ++mt)
#pragma unroll
            for (int ft = 0; ft < 2; ++ft) acc[mt][ft] = (f32x4){0.f,0.f,0.f,0.f};

        for (int fin = 0; fin < DF_; ++fin) {
            const int cbase = v*512 + fin*64 + m;
            const bf16x8 bw0 = *(const bf16x8*)&Wb[((fin*4+g)*F1_ + m)*8];
            const bf16x8 bw1 = *(const bf16x8*)&Wb[((fin*4+g)*F1_ + 16 + m)*8];
#pragma unroll
            for (int mt = 0; mt < 4; ++mt) {
                unsigned ua[4];
#pragma unroll
                for (int p = 0; p < 4; ++p)
                    ua[p] = __builtin_nontemporal_load(&pp[pbase[p] + cbase + mt*16]);
                bf16x8 a;
                __builtin_memcpy(&a, ua, 16);
                acc[mt][0] = __builtin_amdgcn_mfma_f32_16x16x32_bf16(a, bw0, acc[mt][0], 0,0,0);
                acc[mt][1] = __builtin_amdgcn_mfma_f32_16x16x32_bf16(a, bw1, acc[mt][1], 0,0,0);
            }
        }
#pragma unroll
        for (int mt = 0; mt < 4; ++mt)
#pragma unroll
            for (int ft = 0; ft < 2; ++ft) {
                if (vv == 0) pool[mt][ft] = acc[mt][ft];
                else {
#pragma unroll
                    for (int j = 0; j < 4; ++j)
                        pool[mt][ft][j] = fmaxf(pool[mt][ft][j], acc[mt][ft][j]);
                }
            }
    }

#pragma unroll
    for (int mt = 0; mt < 4; ++mt)
#pragma unroll
        for (int ft = 0; ft < 2; ++ft)
#pragma unroll
            for (int j = 0; j < 4; ++j) {
                float mx = fmaxf(pool[mt][ft][j] + bv[ft], 0.f);
                int b = mt*16 + g*4 + j;
                int f = ft*16 + m;
                X0T2[(size_t)(f*64+b)*V2_ + v2] = mx;
            }
}

// ---------- layer-2 Chebyshev: 4 cols/block, f16x4 LDS ping-pong, 1024 thr ----------
template<int V, int THREADS, int MINW>
__global__ __launch_bounds__(THREADS, MINW) void k_cheb2(
        const float* __restrict__ X0T,
        const int* __restrict__ offs,
        const unsigned* __restrict__ ep,
        unsigned* __restrict__ stk) {
    constexpr int RPT = V / THREADS;     // 1
    __shared__ uint2 buf[2*V];
    const int c0 = blockIdx.x*4;
    const int t = threadIdx.x;
    int e0r[RPT], e1r[RPT];
    unsigned tlo[RPT][4];
    unsigned* __restrict__ pl[4];
#pragma unroll
    for (int j = 0; j < 4; ++j) pl[j] = stk + (size_t)(c0+j)*NP_*V;

#pragma unroll
    for (int r = 0; r < RPT; ++r) {
        const int v = r*THREADS + t;
        e0r[r] = offs[v]; e1r[r] = offs[v+1];
        float xj[4];
#pragma unroll
        for (int j = 0; j < 4; ++j) {
            xj[j] = X0T[(size_t)(c0+j)*V + v];
            tlo[r][j] = f2bf(xj[j]);
        }
        __half2 ha = __floats2half2_rn(xj[0], xj[1]);
        __half2 hb = __floats2half2_rn(xj[2], xj[3]);
        buf[v] = make_uint2(*(const unsigned*)&ha, *(const unsigned*)&hb);
    }
    __syncthreads();

    auto step = [&](const uint2* __restrict__ src, uint2* __restrict__ dst,
                    bool first, bool last, int plane) {
#pragma unroll
        for (int r = 0; r < RPT; ++r) {
            const int v = r*THREADS + t;
            float acc[4][4];
#pragma unroll
            for (int j = 0; j < 4; ++j)
#pragma unroll
                for (int i = 0; i < 4; ++i) acc[j][i] = 0.f;
            const int ee0 = e0r[r], ee1 = e1r[r];
            uint4 q = *(const uint4*)&ep[ee0];
            for (int e = ee0; e < ee1; e += 4) {
                const uint4 qn = *(const uint4*)&ep[e + 4];
                const uint2 g0 = *(const uint2*)((const char*)src + (q.x & 0xFFFFu));
                const uint2 g1 = *(const uint2*)((const char*)src + (q.y & 0xFFFFu));
                const uint2 g2 = *(const uint2*)((const char*)src + (q.z & 0xFFFFu));
                const uint2 g3 = *(const uint2*)((const char*)src + (q.w & 0xFFFFu));
                FMA_MIX_LO(acc[0][0], q.x, g0.x); FMA_MIX_HI(acc[1][0], q.x, g0.x);
                FMA_MIX_LO(acc[2][0], q.x, g0.y); FMA_MIX_HI(acc[3][0], q.x, g0.y);
                FMA_MIX_LO(acc[0][1], q.y, g1.x); FMA_MIX_HI(acc[1][1], q.y, g1.x);
                FMA_MIX_LO(acc[2][1], q.y, g1.y); FMA_MIX_HI(acc[3][1], q.y, g1.y);
                FMA_MIX_LO(acc[0][2], q.z, g2.x); FMA_MIX_HI(acc[1][2], q.z, g2.x);
                FMA_MIX_LO(acc[2][2], q.z, g2.y); FMA_MIX_HI(acc[3][2], q.z, g2.y);
                FMA_MIX_LO(acc[0][3], q.w, g3.x); FMA_MIX_HI(acc[1][3], q.w, g3.x);
                FMA_MIX_LO(acc[2][3], q.w, g3.y); FMA_MIX_HI(acc[3][3], q.w, g3.y);
                q = qn;
            }
            float gs[4];
#pragma unroll
            for (int j = 0; j < 4; ++j)
                gs[j] = (acc[j][0]+acc[j][1])+(acc[j][2]+acc[j][3]);
            float xn[4];
            if (first) {
#pragma unroll
                for (int j = 0; j < 4; ++j) xn[j] = gs[j];
            } else {
                const uint2 old = dst[v];
                xn[0] = fmaf(2.f, gs[0], -h2f_lo(old.x));
                xn[1] = fmaf(2.f, gs[1], -h2f_hi(old.x));
                xn[2] = fmaf(2.f, gs[2], -h2f_lo(old.y));
                xn[3] = fmaf(2.f, gs[3], -h2f_hi(old.y));
            }
            if (!last) {
                __half2 ha = __floats2half2_rn(xn[0], xn[1]);
                __half2 hb = __floats2half2_rn(xn[2], xn[3]);
                dst[v] = make_uint2(*(const unsigned*)&ha, *(const unsigned*)&hb);
            }
            unsigned h[4];
#pragma unroll
            for (int j = 0; j < 4; ++j) h[j] = f2bf(xn[j]);
            if (plane < 0) {
#pragma unroll
                for (int j = 0; j < 4; ++j) tlo[r][j] = h[j];
            } else {
#pragma unroll
                for (int j = 0; j < 4; ++j)
                    __builtin_nontemporal_store(tlo[r][j] | (h[j] << 16),
                        &pl[j][(size_t)plane*V + v]);
            }
        }
        __syncthreads();
    };

    step(buf, buf + V, true, false, 0);
    for (int k = 2; k < 24; k += 2) {
        step(buf + V, buf, false, false, -1);
        step(buf, buf + V, false, false, (k + 1) >> 1);
    }
    step(buf + V, buf, false, true, -1);

#pragma unroll
    for (int r = 0; r < RPT; ++r) {
        const int v = r*THREADS + t;
#pragma unroll
        for (int j = 0; j < 4; ++j)
            __builtin_nontemporal_store(tlo[r][j], &pl[j][(size_t)12*V + v]);
    }
}

// ---------- layer-2 MFMA GEMM + relu + pool -> ABF[b][v2*64+f] bf16 ----------
__global__ __launch_bounds__(256) void k_gemm2(const unsigned* __restrict__ STK,
                                               const unsigned short* __restrict__ Wb,
                                               const float* __restrict__ bias,
                                               unsigned short* __restrict__ ABF) {
    const int t = threadIdx.x, lane = t & 63, wave = t >> 6;
    const int b = blockIdx.x;
    const int v0 = blockIdx.y*128 + wave*32;
    const int m = lane & 15, g = lane >> 4;
    int offp[4];
#pragma unroll
    for (int p = 0; p < 4; ++p) {
        int pl = 4*g + p; if (pl > 12) pl = 12;
        offp[p] = pl*V2_ + v0 + m;
    }

    f32x4 acc[2][4];
#pragma unroll
    for (int mt = 0; mt < 2; ++mt)
#pragma unroll
        for (int ft = 0; ft < 4; ++ft) acc[mt][ft] = (f32x4){0.f,0.f,0.f,0.f};

#pragma unroll 4
    for (int fin = 0; fin < F1_; ++fin) {
        const unsigned* sp = STK + (size_t)(fin*64 + b)*(NP_*V2_);
        unsigned ua[4], ub[4];
#pragma unroll
        for (int p = 0; p < 4; ++p) {
            ua[p] = __builtin_nontemporal_load(&sp[offp[p]]);
            ub[p] = __builtin_nontemporal_load(&sp[offp[p] + 16]);
        }
        bf16x8 a0, a1;
        __builtin_memcpy(&a0, ua, 16);
        __builtin_memcpy(&a1, ub, 16);
#pragma unroll
        for (int ft = 0; ft < 4; ++ft) {
            const bf16x8 bw = *(const bf16x8*)&Wb[((fin*4+g)*F2_ + ft*16 + m)*8];
            acc[0][ft] = __builtin_amdgcn_mfma_f32_16x16x32_bf16(a0, bw, acc[0][ft], 0,0,0);
            acc[1][ft] = __builtin_amdgcn_mfma_f32_16x16x32_bf16(a1, bw, acc[1][ft], 0,0,0);
        }
    }
#pragma unroll
    for (int mt = 0; mt < 2; ++mt)
#pragma unroll
        for (int ft = 0; ft < 4; ++ft) {
            f32x4 a = acc[mt][ft];
            float mx = fmaxf(fmaxf(a[0],a[1]), fmaxf(a[2],a[3])) + bias[ft*16 + m];
            mx = fmaxf(mx, 0.f);
            int v2 = blockIdx.y*32 + wave*8 + mt*4 + g;
            ABF[(size_t)b*FCIN_ + v2*64 + ft*16 + m] = f2bf(mx);
        }
}

// ---------- FC1 MFMA: O[64][512] += A[64][16384]·W^T, bias pre-init ----------
__global__ __launch_bounds__(256) void k_fc1_init(const float* __restrict__ bias,
                                                  float* __restrict__ O) {
    int idx = blockIdx.x*256 + threadIdx.x;
    O[idx] = bias[idx & (FC1F_-1)];
}

__global__ __launch_bounds__(256) void k_fc1m(const unsigned short* __restrict__ ABF,
                                              const unsigned short* __restrict__ WBF,
                                              float* __restrict__ O) {
    const int t = threadIdx.x, lane = t & 63, wave = t >> 6;
    const int j0 = blockIdx.x*16;
    const int k0 = blockIdx.y*1024;
    const int m = lane & 15, g = lane >> 4;
    const int m0 = wave*16;
    f32x4 acc = (f32x4){0.f,0.f,0.f,0.f};
#pragma unroll 4
    for (int k = k0; k < k0+1024; k += 32) {
        const bf16x8 a = *(const bf16x8*)&ABF[(size_t)(m0+m)*FCIN_ + k + g*8];
        u32x4 wr = __builtin_nontemporal_load(
            (const u32x4*)&WBF[(size_t)(j0+m)*FCIN_ + k + g*8]);
        bf16x8 w;
        __builtin_memcpy(&w, &wr, 16);
        acc = __builtin_amdgcn_mfma_f32_16x16x32_bf16(a, w, acc, 0,0,0);
    }
#pragma unroll
    for (int r = 0; r < 4; ++r)
        atomicAdd(&O[(size_t)(m0 + g*4 + r)*FC1F_ + j0 + m], acc[r]);
}

// ---------- FC2 (relu on FC1 output applied here) ----------
__global__ void k_fc2(const float* __restrict__ O1, const float* __restrict__ W2,
                      const float* __restrict__ b2, float* __restrict__ out) {
    int c = blockIdx.x;
    int b = threadIdx.x;
    float s = b2[c];
    for (int j = 0; j < FC1F_; ++j)
        s = fmaf(fmaxf(O1[b*FC1F_ + j], 0.f), W2[c*FC1F_ + j], s);
    out[b*FC2F_ + c] = s;
}

extern "C" void kernel_launch(void* const* d_in, const int* in_sizes, int n_in,
                              void* d_out, int out_size, void* d_ws, size_t ws_size,
                              hipStream_t stream) {
    const float* x   = (const float*)d_in[0];
    const int*   l1r = (const int*)d_in[1];
    const int*   l1c = (const int*)d_in[2];
    const float* l1v = (const float*)d_in[3];
    const int*   l2r = (const int*)d_in[4];
    const int*   l2c = (const int*)d_in[5];
    const float* l2v = (const float*)d_in[6];
    const float* w1  = (const float*)d_in[7];
    const float* b1  = (const float*)d_in[8];
    const float* w2  = (const float*)d_in[9];
    const float* b2  = (const float*)d_in[10];
    const float* fw1 = (const float*)d_in[11];
    const float* fb1 = (const float*)d_in[12];
    const float* fw2 = (const float*)d_in[13];
    const float* fb2 = (const float*)d_in[14];
    float* out = (float*)d_out;

    char* wsp = (char*)d_ws;
    size_t off = 0;
    auto alloc = [&](size_t bytes) -> void* {
        void* p = wsp + off;
        off += (bytes + 255) & ~size_t(255);
        return p;
    };
    // shared big buffer: ppstk (layer-1 pair planes, 109MB) then STACK (layer-2, 109MB),
    // stream-ordered reuse (gemm1c reads finish before cheb2 writes).
    void*     STKU  = alloc((size_t)C2_*NP_*V2_*4);                     // 109 MB
    unsigned* ppstk = (unsigned*)STKU;
    unsigned* STACK = (unsigned*)STKU;
    unsigned short* XB0   = (unsigned short*)alloc((size_t)V1_*C1_*2);  // 4 MB
    unsigned short* XB1   = (unsigned short*)alloc((size_t)V1_*C1_*2);  // 4 MB
    float*    X0T2  = (float*)alloc((size_t)C2_*V2_*4);                 // 8 MB
    unsigned short* ABF = (unsigned short*)alloc((size_t)B_*FCIN_*2);   // 2 MB
    unsigned short* WBF = (unsigned short*)alloc((size_t)FC1F_*FCIN_*2);// 16.7 MB
    float*    FC1O  = (float*)alloc((size_t)B_*FC1F_*4);
    unsigned short* WB1 = (unsigned short*)alloc((size_t)DF_*4*F1_*8*2);
    unsigned short* WB2 = (unsigned short*)alloc((size_t)F1_*4*F2_*8*2);
    int*      cnt1  = (int*)alloc(V1_*4);
    int*      offs1 = (int*)alloc((V1_+1)*4);
    int*      cur1  = (int*)alloc(V1_*4);
    unsigned* ep1   = (unsigned*)alloc((size_t)(E1_ + 4*V1_ + 8)*4);
    int*      cnt2  = (int*)alloc(V2_*4);
    int*      offs2 = (int*)alloc((V2_+1)*4);
    int*      cur2  = (int*)alloc(V2_*4);
    unsigned* ep2   = (unsigned*)alloc((size_t)(E2_ + 4*V2_ + 8)*4);

    // --- CSR build both layers + W prep ---
    hipMemsetAsync(cnt1, 0, V1_*4, stream);
    hipMemsetAsync(ep1, 0, (size_t)(E1_ + 4*V1_ + 8)*4, stream);
    hipMemsetAsync(cnt2, 0, V2_*4, stream);
    hipMemsetAsync(ep2, 0, (size_t)(E2_ + 4*V2_ + 8)*4, stream);
    hipLaunchKernelGGL(k_count,   dim3(E1_/256), dim3(256), 0, stream, l1r, E1_, cnt1);
    hipLaunchKernelGGL(k_scan,    dim3(1),       dim3(256), 0, stream, cnt1, V1_, offs1, cur1);
    hipLaunchKernelGGL(k_scatter, dim3(E1_/256), dim3(256), 0, stream, l1r, l1c, l1v, E1_, 0, cur1, ep1);
    hipLaunchKernelGGL(k_count,   dim3(E2_/256), dim3(256), 0, stream, l2r, E2_, cnt2);
    hipLaunchKernelGGL(k_scan,    dim3(1),       dim3(256), 0, stream, cnt2, V2_, offs2, cur2);
    hipLaunchKernelGGL(k_scatter, dim3(E2_/256), dim3(256), 0, stream, l2r, l2c, l2v, E2_, 3, cur2, ep2);
    hipLaunchKernelGGL((k_wprep<DF_,F1_>), dim3(DF_*4*F1_*8/256), dim3(256), 0, stream, w1, WB1);
    hipLaunchKernelGGL((k_wprep<F1_,F2_>), dim3(F1_*4*F2_*8/256), dim3(256), 0, stream, w2, WB2);
    hipLaunchKernelGGL(k_wprep_fc, dim3(FC1F_*FCIN_/1024), dim3(256), 0, stream, fw1, WBF);

    // --- layer 1: dual-cheb, one launch per k-step ---
    hipLaunchKernelGGL(k_transpose_rm, dim3(V1_/16), dim3(256), 0, stream, x, (unsigned*)XB0);
    for (int k = 1; k <= 24; ++k) {
        unsigned short* src = (k & 1) ? XB0 : XB1;   // x_{k-1}
        unsigned short* own = (k & 1) ? XB1 : XB0;   // x_{k-2} in, x_k out
        hipLaunchKernelGGL(k_dcheb1, dim3(V1_/8), dim3(1024), 0, stream,
                           k, src, own, ppstk, offs1, ep1);
    }
    hipLaunchKernelGGL(k_gemm1c, dim3(V2_/4), dim3(256), 0, stream, ppstk, WB1, b1, X0T2);

    // --- layer 2 ---
    hipLaunchKernelGGL((k_cheb2<V2_,1024,8>), dim3(C2_/4), dim3(1024), 0, stream,
                       X0T2, offs2, ep2, STACK);
    hipLaunchKernelGGL(k_gemm2, dim3(64, 8), dim3(256), 0, stream, STACK, WB2, b2, ABF);

    // --- FC ---
    hipLaunchKernelGGL(k_fc1_init, dim3(B_*FC1F_/256), dim3(256), 0, stream, fb1, FC1O);
    hipLaunchKernelGGL(k_fc1m, dim3(32, 16), dim3(256), 0, stream, ABF, WBF, FC1O);
    hipLaunchKernelGGL(k_fc2, dim3(FC2F_), dim3(B_), 0, stream, FC1O, fw2, fb2, out);
}

// Round 14
// 546.911 us; speedup vs baseline: 1.0504x; 1.0504x over previous
//
#include <hip/hip_runtime.h>
#include <hip/hip_fp16.h>

#define B_    64
#define V1_   4096
#define V2_   1024
#define DF_   8
#define K_    25
#define NP_   13
#define F1_   32
#define F2_   64
#define FC1F_ 512
#define FC2F_ 10
#define E1_   65536
#define E2_   16384
#define C1_   512
#define C2_   2048
#define FCIN_ 16384

typedef short bf16x8 __attribute__((ext_vector_type(8)));
typedef float f32x4  __attribute__((ext_vector_type(4)));
typedef unsigned u32x4 __attribute__((ext_vector_type(4)));

// acc += f16(hi16 of q) * f16(lo16 of g)   [f32 accumulate]
#define FMA_MIX_LO(acc, qv, gv) \
    asm("v_fma_mix_f32 %0, %1, %2, %0 op_sel:[1,0,0] op_sel_hi:[1,1,0]" \
        : "+v"(acc) : "v"(qv), "v"(gv))
// acc += f16(hi16 of q) * f16(hi16 of g)
#define FMA_MIX_HI(acc, qv, gv) \
    asm("v_fma_mix_f32 %0, %1, %2, %0 op_sel:[1,1,0] op_sel_hi:[1,1,0]" \
        : "+v"(acc) : "v"(qv), "v"(gv))

__device__ __forceinline__ unsigned short f2bf(float x) {
    unsigned u = __float_as_uint(x);
    u += 0x7FFFu + ((u >> 16) & 1u);
    return (unsigned short)(u >> 16);
}
__device__ __forceinline__ float h2f_lo(unsigned u) {
    return __half2float(__ushort_as_half((unsigned short)(u & 0xFFFFu)));
}
__device__ __forceinline__ float h2f_hi(unsigned u) {
    return __half2float(__ushort_as_half((unsigned short)(u >> 16)));
}

// ---------- input transpose: x[b,v,fin] -> XP[v][c=fin*64+b] f16 + stk16 plane0 bf16 ----------
__global__ __launch_bounds__(256) void k_transpose_rm(const float* __restrict__ x,
                                                      unsigned* __restrict__ XP,
                                                      unsigned* __restrict__ stk0) {
    __shared__ float tsh[DF_][B_][16];
    const int t = threadIdx.x;
    const int v0 = blockIdx.x * 16;
    for (int rep = 0; rep < 4; ++rep) {
        int idx = rep*256 + t;
        int b = idx >> 4, vv = idx & 15;
        const float4* p = (const float4*)&x[((size_t)b*V1_ + v0 + vv)*DF_];
        float4 a0 = p[0], a1 = p[1];
        tsh[0][b][vv]=a0.x; tsh[1][b][vv]=a0.y; tsh[2][b][vv]=a0.z; tsh[3][b][vv]=a0.w;
        tsh[4][b][vv]=a1.x; tsh[5][b][vv]=a1.y; tsh[6][b][vv]=a1.z; tsh[7][b][vv]=a1.w;
    }
    __syncthreads();
    for (int rep = 0; rep < 16; ++rep) {
        int idx = rep*256 + t;
        int c2 = idx & 255, vv = idx >> 8;
        int c = c2*2, fin = c >> 6, b = c & 63;
        float xa = tsh[fin][b][vv], xb = tsh[fin][b+1][vv];
        __half2 hh = __floats2half2_rn(xa, xb);
        XP[(size_t)(v0+vv)*256 + c2] = *(const unsigned*)&hh;
        __builtin_nontemporal_store(
            (unsigned)f2bf(xa) | ((unsigned)f2bf(xb) << 16),
            &stk0[(size_t)(v0+vv)*256 + c2]);
    }
}

// ---------- CSR build (padded to 4-edge alignment, packed 4B edges) ----------
__global__ __launch_bounds__(256) void k_count(const int* __restrict__ rows, int E,
                                               int* __restrict__ cnt) {
    int e = blockIdx.x*256 + threadIdx.x;
    if (e < E) atomicAdd(&cnt[rows[e]], 1);
}

__global__ __launch_bounds__(256) void k_scan(const int* __restrict__ cnt, int V,
                                              int* __restrict__ offs, int* __restrict__ cursor) {
    __shared__ int psum[256];
    int t = threadIdx.x;
    int chunk = V >> 8;
    int lo = t*chunk;
    int s = 0;
    for (int i = lo; i < lo+chunk; ++i) s += (cnt[i] + 3) & ~3;
    psum[t] = s;
    __syncthreads();
    for (int off = 1; off < 256; off <<= 1) {
        int val = (t >= off) ? psum[t-off] : 0;
        __syncthreads();
        psum[t] += val;
        __syncthreads();
    }
    int run = (t == 0) ? 0 : psum[t-1];
    for (int i = lo; i < lo+chunk; ++i) {
        offs[i] = run; cursor[i] = run;
        run += (cnt[i] + 3) & ~3;
    }
    if (t == 255) offs[V] = run;
}

// edge payload: {f16 weight hi16, (col<<shift) lo16}
__global__ __launch_bounds__(256) void k_scatter(const int* __restrict__ rows,
                                                 const int* __restrict__ cols,
                                                 const float* __restrict__ vals, int E,
                                                 int shift,
                                                 int* __restrict__ cursor,
                                                 unsigned* __restrict__ ep) {
    int e = blockIdx.x*256 + threadIdx.x;
    if (e < E) {
        int p = atomicAdd(&cursor[rows[e]], 1);
        unsigned hv = (unsigned)__half_as_ushort(__float2half(vals[e]));
        ep[p] = (hv << 16) | ((unsigned)cols[e] << shift);
    }
}

// ---------- layer-1 dual Chebyshev step: 1 wave per row, all 512 cols ----------
// stk16[k][v][c] bf16, written via non-temporal stores (stream-once, no L2 allocate).
__global__ __launch_bounds__(512) void k_dcheb1(int k,
        const unsigned short* __restrict__ Xsrc,
        unsigned short* __restrict__ Xown,
        unsigned short* __restrict__ stk16,
        const int* __restrict__ offs,
        const unsigned* __restrict__ ep) {
    const int t = threadIdx.x;
    const int lane = t & 63;
    const int v = blockIdx.x*8 + (t >> 6);
    const int e0 = offs[v], e1 = offs[v+1];
    const unsigned loff = (unsigned)lane * 16u;
    float acc[8];
#pragma unroll
    for (int j = 0; j < 8; ++j) acc[j] = 0.f;
    const char* srcb = (const char*)Xsrc;

    for (int e = e0; e < e1; e += 4) {
        const uint4 q = *(const uint4*)&ep[e];
        const uint4 g0 = *(const uint4*)(srcb + ((q.x & 0xFFFFu)*1024u + loff));
        const uint4 g1 = *(const uint4*)(srcb + ((q.y & 0xFFFFu)*1024u + loff));
        const uint4 g2 = *(const uint4*)(srcb + ((q.z & 0xFFFFu)*1024u + loff));
        const uint4 g3 = *(const uint4*)(srcb + ((q.w & 0xFFFFu)*1024u + loff));
        FMA_MIX_LO(acc[0], q.x, g0.x); FMA_MIX_HI(acc[1], q.x, g0.x);
        FMA_MIX_LO(acc[2], q.x, g0.y); FMA_MIX_HI(acc[3], q.x, g0.y);
        FMA_MIX_LO(acc[4], q.x, g0.z); FMA_MIX_HI(acc[5], q.x, g0.z);
        FMA_MIX_LO(acc[6], q.x, g0.w); FMA_MIX_HI(acc[7], q.x, g0.w);
        FMA_MIX_LO(acc[0], q.y, g1.x); FMA_MIX_HI(acc[1], q.y, g1.x);
        FMA_MIX_LO(acc[2], q.y, g1.y); FMA_MIX_HI(acc[3], q.y, g1.y);
        FMA_MIX_LO(acc[4], q.y, g1.z); FMA_MIX_HI(acc[5], q.y, g1.z);
        FMA_MIX_LO(acc[6], q.y, g1.w); FMA_MIX_HI(acc[7], q.y, g1.w);
        FMA_MIX_LO(acc[0], q.z, g2.x); FMA_MIX_HI(acc[1], q.z, g2.x);
        FMA_MIX_LO(acc[2], q.z, g2.y); FMA_MIX_HI(acc[3], q.z, g2.y);
        FMA_MIX_LO(acc[4], q.z, g2.z); FMA_MIX_HI(acc[5], q.z, g2.z);
        FMA_MIX_LO(acc[6], q.z, g2.w); FMA_MIX_HI(acc[7], q.z, g2.w);
        FMA_MIX_LO(acc[0], q.w, g3.x); FMA_MIX_HI(acc[1], q.w, g3.x);
        FMA_MIX_LO(acc[2], q.w, g3.y); FMA_MIX_HI(acc[3], q.w, g3.y);
        FMA_MIX_LO(acc[4], q.w, g3.z); FMA_MIX_HI(acc[5], q.w, g3.z);
        FMA_MIX_LO(acc[6], q.w, g3.w); FMA_MIX_HI(acc[7], q.w, g3.w);
    }

    float xn[8];
    if (k > 1) {
        const uint4 old = *(const uint4*)((const char*)Xown + ((size_t)v*1024 + loff));
        xn[0] = fmaf(2.f, acc[0], -h2f_lo(old.x));
        xn[1] = fmaf(2.f, acc[1], -h2f_hi(old.x));
        xn[2] = fmaf(2.f, acc[2], -h2f_lo(old.y));
        xn[3] = fmaf(2.f, acc[3], -h2f_hi(old.y));
        xn[4] = fmaf(2.f, acc[4], -h2f_lo(old.z));
        xn[5] = fmaf(2.f, acc[5], -h2f_hi(old.z));
        xn[6] = fmaf(2.f, acc[6], -h2f_lo(old.w));
        xn[7] = fmaf(2.f, acc[7], -h2f_hi(old.w));
    } else {
#pragma unroll
        for (int j = 0; j < 8; ++j) xn[j] = acc[j];
    }

    uint4 hp;   // new f16 state — REGULAR store (next step re-reads it; keep in L2)
    { __half2 h0 = __floats2half2_rn(xn[0], xn[1]); hp.x = *(const unsigned*)&h0;
      __half2 h1 = __floats2half2_rn(xn[2], xn[3]); hp.y = *(const unsigned*)&h1;
      __half2 h2 = __floats2half2_rn(xn[4], xn[5]); hp.z = *(const unsigned*)&h2;
      __half2 h3 = __floats2half2_rn(xn[6], xn[7]); hp.w = *(const unsigned*)&h3; }
    *(uint4*)((char*)Xown + ((size_t)v*1024 + loff)) = hp;

    u32x4 bp;   // stack plane — NON-TEMPORAL (write-once stream, read by gemm1b later)
    bp.x = (unsigned)f2bf(xn[0]) | ((unsigned)f2bf(xn[1]) << 16);
    bp.y = (unsigned)f2bf(xn[2]) | ((unsigned)f2bf(xn[3]) << 16);
    bp.z = (unsigned)f2bf(xn[4]) | ((unsigned)f2bf(xn[5]) << 16);
    bp.w = (unsigned)f2bf(xn[6]) | ((unsigned)f2bf(xn[7]) << 16);
    __builtin_nontemporal_store(bp,
        (u32x4*)((char*)stk16 + (((size_t)k*V1_ + v)*1024 + loff)));
}

// ---------- W prep (conv): Wb[fin][g][f][kk] = bf16(W[f][fin*25+g*8+kk]), 0-padded ----------
template<int FIN, int F>
__global__ __launch_bounds__(256) void k_wprep(const float* __restrict__ W,
                                               unsigned short* __restrict__ Wb) {
    int idx = blockIdx.x*256 + threadIdx.x;
    int kk  = idx & 7;
    int f   = (idx >> 3) % F;
    int g   = (idx >> 3) / F % 4;
    int fin = idx / (8*F*4);
    int k = g*8 + kk;
    Wb[idx] = (k < K_) ? f2bf(W[(size_t)f*(FIN*K_) + fin*K_ + k]) : 0;
}

// ---------- W prep (fc1): f32 -> bf16 flat copy ----------
__global__ __launch_bounds__(256) void k_wprep_fc(const float* __restrict__ W,
                                                  unsigned short* __restrict__ Wb) {
    int idx = (blockIdx.x*256 + threadIdx.x)*4;
    float4 w = *(const float4*)&W[idx];
    ushort4 o;
    o.x = f2bf(w.x); o.y = f2bf(w.y); o.z = f2bf(w.z); o.w = f2bf(w.w);
    *(ushort4*)&Wb[idx] = o;
}

// ---------- layer-1 MFMA GEMM (stk16 [k][v][c]) + relu + pool -> X0T2[(f*64+b)][v2] ----------
__global__ __launch_bounds__(256) void k_gemm1b(const unsigned short* __restrict__ stk16,
                                                const unsigned short* __restrict__ Wb,
                                                const float* __restrict__ bias,
                                                float* __restrict__ X0T2) {
    const int t = threadIdx.x, lane = t & 63, wave = t >> 6;
    const int v2 = blockIdx.x*4 + wave;
    const int m = lane & 15, g = lane >> 4;
    int kbase[8];
#pragma unroll
    for (int j = 0; j < 8; ++j) {
        int kq = g*8 + j; if (kq > 24) kq = 24;
        kbase[j] = kq * (V1_*C1_);
    }
    float bv[2] = { bias[m], bias[16+m] };
    f32x4 pool[4][2];

    for (int vv = 0; vv < 4; ++vv) {
        const int v = v2*4 + vv;
        f32x4 acc[4][2];
#pragma unroll
        for (int mt = 0; mt < 4; ++mt)
#pragma unroll
            for (int ft = 0; ft < 2; ++ft) acc[mt][ft] = (f32x4){0.f,0.f,0.f,0.f};

        for (int fin = 0; fin < DF_; ++fin) {
            const int cbase = v*C1_ + fin*64 + m;
            const bf16x8 bw0 = *(const bf16x8*)&Wb[((fin*4+g)*F1_ + m)*8];
            const bf16x8 bw1 = *(const bf16x8*)&Wb[((fin*4+g)*F1_ + 16 + m)*8];
#pragma unroll
            for (int mt = 0; mt < 4; ++mt) {
                unsigned short au[8];
#pragma unroll
                for (int j = 0; j < 8; ++j)
                    au[j] = stk16[(size_t)(kbase[j] + cbase + mt*16)];
                bf16x8 a;
                __builtin_memcpy(&a, au, 16);
                acc[mt][0] = __builtin_amdgcn_mfma_f32_16x16x32_bf16(a, bw0, acc[mt][0], 0,0,0);
                acc[mt][1] = __builtin_amdgcn_mfma_f32_16x16x32_bf16(a, bw1, acc[mt][1], 0,0,0);
            }
        }
#pragma unroll
        for (int mt = 0; mt < 4; ++mt)
#pragma unroll
            for (int ft = 0; ft < 2; ++ft) {
                if (vv == 0) pool[mt][ft] = acc[mt][ft];
                else {
#pragma unroll
                    for (int j = 0; j < 4; ++j)
                        pool[mt][ft][j] = fmaxf(pool[mt][ft][j], acc[mt][ft][j]);
                }
            }
    }

#pragma unroll
    for (int mt = 0; mt < 4; ++mt)
#pragma unroll
        for (int ft = 0; ft < 2; ++ft)
#pragma unroll
            for (int j = 0; j < 4; ++j) {
                float mx = fmaxf(pool[mt][ft][j] + bv[ft], 0.f);
                int b = mt*16 + g*4 + j;
                int f = ft*16 + m;
                X0T2[(size_t)(f*64+b)*V2_ + v2] = mx;
            }
}

// ---------- layer-2 Chebyshev: 4 cols/block, f16x4 LDS ping-pong (r8/r12 version) ----------
template<int V, int THREADS, int MINW>
__global__ __launch_bounds__(THREADS, MINW) void k_cheb2(
        const float* __restrict__ X0T,
        const int* __restrict__ offs,
        const unsigned* __restrict__ ep,
        unsigned* __restrict__ stk) {
    constexpr int RPT = V / THREADS;     // 2
    __shared__ uint2 buf[2*V];
    const int c0 = blockIdx.x*4;
    const int t = threadIdx.x;
    int e0r[RPT], e1r[RPT];
    unsigned tlo[RPT][4];
    unsigned* __restrict__ pl[4];
#pragma unroll
    for (int j = 0; j < 4; ++j) pl[j] = stk + (size_t)(c0+j)*NP_*V;

#pragma unroll
    for (int r = 0; r < RPT; ++r) {
        const int v = r*THREADS + t;
        e0r[r] = offs[v]; e1r[r] = offs[v+1];
        float xj[4];
#pragma unroll
        for (int j = 0; j < 4; ++j) {
            xj[j] = X0T[(size_t)(c0+j)*V + v];
            tlo[r][j] = f2bf(xj[j]);
        }
        __half2 ha = __floats2half2_rn(xj[0], xj[1]);
        __half2 hb = __floats2half2_rn(xj[2], xj[3]);
        buf[v] = make_uint2(*(const unsigned*)&ha, *(const unsigned*)&hb);
    }
    __syncthreads();

    auto step = [&](const uint2* __restrict__ src, uint2* __restrict__ dst,
                    bool first, bool last, int plane) {
#pragma unroll
        for (int r = 0; r < RPT; ++r) {
            const int v = r*THREADS + t;
            float acc[4][4];
#pragma unroll
            for (int j = 0; j < 4; ++j)
#pragma unroll
                for (int i = 0; i < 4; ++i) acc[j][i] = 0.f;
            const int ee0 = e0r[r], ee1 = e1r[r];
            uint4 q = *(const uint4*)&ep[ee0];
            for (int e = ee0; e < ee1; e += 4) {
                const uint4 qn = *(const uint4*)&ep[e + 4];
                const uint2 g0 = *(const uint2*)((const char*)src + (q.x & 0xFFFFu));
                const uint2 g1 = *(const uint2*)((const char*)src + (q.y & 0xFFFFu));
                const uint2 g2 = *(const uint2*)((const char*)src + (q.z & 0xFFFFu));
                const uint2 g3 = *(const uint2*)((const char*)src + (q.w & 0xFFFFu));
                FMA_MIX_LO(acc[0][0], q.x, g0.x); FMA_MIX_HI(acc[1][0], q.x, g0.x);
                FMA_MIX_LO(acc[2][0], q.x, g0.y); FMA_MIX_HI(acc[3][0], q.x, g0.y);
                FMA_MIX_LO(acc[0][1], q.y, g1.x); FMA_MIX_HI(acc[1][1], q.y, g1.x);
                FMA_MIX_LO(acc[2][1], q.y, g1.y); FMA_MIX_HI(acc[3][1], q.y, g1.y);
                FMA_MIX_LO(acc[0][2], q.z, g2.x); FMA_MIX_HI(acc[1][2], q.z, g2.x);
                FMA_MIX_LO(acc[2][2], q.z, g2.y); FMA_MIX_HI(acc[3][2], q.z, g2.y);
                FMA_MIX_LO(acc[0][3], q.w, g3.x); FMA_MIX_HI(acc[1][3], q.w, g3.x);
                FMA_MIX_LO(acc[2][3], q.w, g3.y); FMA_MIX_HI(acc[3][3], q.w, g3.y);
                q = qn;
            }
            float gs[4];
#pragma unroll
            for (int j = 0; j < 4; ++j)
                gs[j] = (acc[j][0]+acc[j][1])+(acc[j][2]+acc[j][3]);
            float xn[4];
            if (first) {
#pragma unroll
                for (int j = 0; j < 4; ++j) xn[j] = gs[j];
            } else {
                const uint2 old = dst[v];
                xn[0] = fmaf(2.f, gs[0], -h2f_lo(old.x));
                xn[1] = fmaf(2.f, gs[1], -h2f_hi(old.x));
                xn[2] = fmaf(2.f, gs[2], -h2f_lo(old.y));
                xn[3] = fmaf(2.f, gs[3], -h2f_hi(old.y));
            }
            if (!last) {
                __half2 ha = __floats2half2_rn(xn[0], xn[1]);
                __half2 hb = __floats2half2_rn(xn[2], xn[3]);
                dst[v] = make_uint2(*(const unsigned*)&ha, *(const unsigned*)&hb);
            }
            unsigned h[4];
#pragma unroll
            for (int j = 0; j < 4; ++j) h[j] = f2bf(xn[j]);
            if (plane < 0) {
#pragma unroll
                for (int j = 0; j < 4; ++j) tlo[r][j] = h[j];
            } else {
#pragma unroll
                for (int j = 0; j < 4; ++j)
                    __builtin_nontemporal_store(tlo[r][j] | (h[j] << 16),
                        &pl[j][(size_t)plane*V + v]);
            }
        }
        __syncthreads();
    };

    step(buf, buf + V, true, false, 0);
    for (int k = 2; k < 24; k += 2) {
        step(buf + V, buf, false, false, -1);
        step(buf, buf + V, false, false, (k + 1) >> 1);
    }
    step(buf + V, buf, false, true, -1);

#pragma unroll
    for (int r = 0; r < RPT; ++r) {
        const int v = r*THREADS + t;
#pragma unroll
        for (int j = 0; j < 4; ++j)
            __builtin_nontemporal_store(tlo[r][j], &pl[j][(size_t)12*V + v]);
    }
}

// ---------- layer-2 MFMA GEMM + relu + pool -> ABF[b][v2*64+f] bf16 ----------
__global__ __launch_bounds__(256) void k_gemm2(const unsigned* __restrict__ STK,
                                               const unsigned short* __restrict__ Wb,
                                               const float* __restrict__ bias,
                                               unsigned short* __restrict__ ABF) {
    const int t = threadIdx.x, lane = t & 63, wave = t >> 6;
    const int b = blockIdx.x;
    const int v0 = blockIdx.y*128 + wave*32;
    const int m = lane & 15, g = lane >> 4;
    int offp[4];
#pragma unroll
    for (int p = 0; p < 4; ++p) {
        int pl = 4*g + p; if (pl > 12) pl = 12;
        offp[p] = pl*V2_ + v0 + m;
    }

    f32x4 acc[2][4];
#pragma unroll
    for (int mt = 0; mt < 2; ++mt)
#pragma unroll
        for (int ft = 0; ft < 4; ++ft) acc[mt][ft] = (f32x4){0.f,0.f,0.f,0.f};

#pragma unroll 4
    for (int fin = 0; fin < F1_; ++fin) {
        const unsigned* sp = STK + (size_t)(fin*64 + b)*(NP_*V2_);
        unsigned ua[4], ub[4];
#pragma unroll
        for (int p = 0; p < 4; ++p) { ua[p] = sp[offp[p]]; ub[p] = sp[offp[p] + 16]; }
        bf16x8 a0, a1;
        __builtin_memcpy(&a0, ua, 16);
        __builtin_memcpy(&a1, ub, 16);
#pragma unroll
        for (int ft = 0; ft < 4; ++ft) {
            const bf16x8 bw = *(const bf16x8*)&Wb[((fin*4+g)*F2_ + ft*16 + m)*8];
            acc[0][ft] = __builtin_amdgcn_mfma_f32_16x16x32_bf16(a0, bw, acc[0][ft], 0,0,0);
            acc[1][ft] = __builtin_amdgcn_mfma_f32_16x16x32_bf16(a1, bw, acc[1][ft], 0,0,0);
        }
    }
#pragma unroll
    for (int mt = 0; mt < 2; ++mt)
#pragma unroll
        for (int ft = 0; ft < 4; ++ft) {
            f32x4 a = acc[mt][ft];
            float mx = fmaxf(fmaxf(a[0],a[1]), fmaxf(a[2],a[3])) + bias[ft*16 + m];
            mx = fmaxf(mx, 0.f);
            int v2 = blockIdx.y*32 + wave*8 + mt*4 + g;
            ABF[(size_t)b*FCIN_ + v2*64 + ft*16 + m] = f2bf(mx);
        }
}

// ---------- FC1 MFMA: O[64][512] += A[64][16384]·W^T, bias pre-init ----------
__global__ __launch_bounds__(256) void k_fc1_init(const float* __restrict__ bias,
                                                  float* __restrict__ O) {
    int idx = blockIdx.x*256 + threadIdx.x;
    O[idx] = bias[idx & (FC1F_-1)];
}

__global__ __launch_bounds__(256) void k_fc1m(const unsigned short* __restrict__ ABF,
                                              const unsigned short* __restrict__ WBF,
                                              float* __restrict__ O) {
    const int t = threadIdx.x, lane = t & 63, wave = t >> 6;
    const int j0 = blockIdx.x*16;
    const int k0 = blockIdx.y*1024;
    const int m = lane & 15, g = lane >> 4;
    const int m0 = wave*16;
    f32x4 acc = (f32x4){0.f,0.f,0.f,0.f};
#pragma unroll 4
    for (int k = k0; k < k0+1024; k += 32) {
        const bf16x8 a = *(const bf16x8*)&ABF[(size_t)(m0+m)*FCIN_ + k + g*8];
        const bf16x8 w = *(const bf16x8*)&WBF[(size_t)(j0+m)*FCIN_ + k + g*8];
        acc = __builtin_amdgcn_mfma_f32_16x16x32_bf16(a, w, acc, 0,0,0);
    }
#pragma unroll
    for (int r = 0; r < 4; ++r)
        atomicAdd(&O[(size_t)(m0 + g*4 + r)*FC1F_ + j0 + m], acc[r]);
}

// ---------- FC2 (relu on FC1 output applied here) ----------
__global__ void k_fc2(const float* __restrict__ O1, const float* __restrict__ W2,
                      const float* __restrict__ b2, float* __restrict__ out) {
    int c = blockIdx.x;
    int b = threadIdx.x;
    float s = b2[c];
    for (int j = 0; j < FC1F_; ++j)
        s = fmaf(fmaxf(O1[b*FC1F_ + j], 0.f), W2[c*FC1F_ + j], s);
    out[b*FC2F_ + c] = s;
}

extern "C" void kernel_launch(void* const* d_in, const int* in_sizes, int n_in,
                              void* d_out, int out_size, void* d_ws, size_t ws_size,
                              hipStream_t stream) {
    const float* x   = (const float*)d_in[0];
    const int*   l1r = (const int*)d_in[1];
    const int*   l1c = (const int*)d_in[2];
    const float* l1v = (const float*)d_in[3];
    const int*   l2r = (const int*)d_in[4];
    const int*   l2c = (const int*)d_in[5];
    const float* l2v = (const float*)d_in[6];
    const float* w1  = (const float*)d_in[7];
    const float* b1  = (const float*)d_in[8];
    const float* w2  = (const float*)d_in[9];
    const float* b2  = (const float*)d_in[10];
    const float* fw1 = (const float*)d_in[11];
    const float* fb1 = (const float*)d_in[12];
    const float* fw2 = (const float*)d_in[13];
    const float* fb2 = (const float*)d_in[14];
    float* out = (float*)d_out;

    char* wsp = (char*)d_ws;
    size_t off = 0;
    auto alloc = [&](size_t bytes) -> void* {
        void* p = wsp + off;
        off += (bytes + 255) & ~size_t(255);
        return p;
    };
    // shared big buffer: stk16 (layer-1) then STACK (layer-2), stream-ordered reuse.
    void*     STKU  = alloc((size_t)C2_*NP_*V2_*4);                     // 109 MB
    unsigned short* stk16 = (unsigned short*)STKU;
    unsigned*       STACK = (unsigned*)STKU;
    unsigned short* XB0   = (unsigned short*)alloc((size_t)V1_*C1_*2);  // 4 MB
    unsigned short* XB1   = (unsigned short*)alloc((size_t)V1_*C1_*2);  // 4 MB
    float*    X0T2  = (float*)alloc((size_t)C2_*V2_*4);                 // 8 MB
    unsigned short* ABF = (unsigned short*)alloc((size_t)B_*FCIN_*2);   // 2 MB
    unsigned short* WBF = (unsigned short*)alloc((size_t)FC1F_*FCIN_*2);// 16.7 MB
    float*    FC1O  = (float*)alloc((size_t)B_*FC1F_*4);
    unsigned short* WB1 = (unsigned short*)alloc((size_t)DF_*4*F1_*8*2);
    unsigned short* WB2 = (unsigned short*)alloc((size_t)F1_*4*F2_*8*2);
    int*      cnt1  = (int*)alloc(V1_*4);
    int*      offs1 = (int*)alloc((V1_+1)*4);
    int*      cur1  = (int*)alloc(V1_*4);
    unsigned* ep1   = (unsigned*)alloc((size_t)(E1_ + 4*V1_ + 8)*4);
    int*      cnt2  = (int*)alloc(V2_*4);
    int*      offs2 = (int*)alloc((V2_+1)*4);
    int*      cur2  = (int*)alloc(V2_*4);
    unsigned* ep2   = (unsigned*)alloc((size_t)(E2_ + 4*V2_ + 8)*4);

    // --- CSR build both layers + W prep ---
    hipMemsetAsync(cnt1, 0, V1_*4, stream);
    hipMemsetAsync(ep1, 0, (size_t)(E1_ + 4*V1_ + 8)*4, stream);
    hipMemsetAsync(cnt2, 0, V2_*4, stream);
    hipMemsetAsync(ep2, 0, (size_t)(E2_ + 4*V2_ + 8)*4, stream);
    hipLaunchKernelGGL(k_count,   dim3(E1_/256), dim3(256), 0, stream, l1r, E1_, cnt1);
    hipLaunchKernelGGL(k_scan,    dim3(1),       dim3(256), 0, stream, cnt1, V1_, offs1, cur1);
    hipLaunchKernelGGL(k_scatter, dim3(E1_/256), dim3(256), 0, stream, l1r, l1c, l1v, E1_, 0, cur1, ep1);
    hipLaunchKernelGGL(k_count,   dim3(E2_/256), dim3(256), 0, stream, l2r, E2_, cnt2);
    hipLaunchKernelGGL(k_scan,    dim3(1),       dim3(256), 0, stream, cnt2, V2_, offs2, cur2);
    hipLaunchKernelGGL(k_scatter, dim3(E2_/256), dim3(256), 0, stream, l2r, l2c, l2v, E2_, 3, cur2, ep2);
    hipLaunchKernelGGL((k_wprep<DF_,F1_>), dim3(DF_*4*F1_*8/256), dim3(256), 0, stream, w1, WB1);
    hipLaunchKernelGGL((k_wprep<F1_,F2_>), dim3(F1_*4*F2_*8/256), dim3(256), 0, stream, w2, WB2);
    hipLaunchKernelGGL(k_wprep_fc, dim3(FC1F_*FCIN_/1024), dim3(256), 0, stream, fw1, WBF);

    // --- layer 1: dual-cheb, one launch per k-step ---
    hipLaunchKernelGGL(k_transpose_rm, dim3(V1_/16), dim3(256), 0, stream,
                       x, (unsigned*)XB0, (unsigned*)stk16);
    for (int k = 1; k <= 24; ++k) {
        unsigned short* src = (k & 1) ? XB0 : XB1;
        unsigned short* own = (k & 1) ? XB1 : XB0;
        hipLaunchKernelGGL(k_dcheb1, dim3(V1_/8), dim3(512), 0, stream,
                           k, src, own, stk16, offs1, ep1);
    }
    hipLaunchKernelGGL(k_gemm1b, dim3(V2_/4), dim3(256), 0, stream, stk16, WB1, b1, X0T2);

    // --- layer 2 ---
    hipLaunchKernelGGL((k_cheb2<V2_,512,4>), dim3(C2_/4), dim3(512), 0, stream,
                       X0T2, offs2, ep2, STACK);
    hipLaunchKernelGGL(k_gemm2, dim3(64, 8), dim3(256), 0, stream, STACK, WB2, b2, ABF);

    // --- FC ---
    hipLaunchKernelGGL(k_fc1_init, dim3(B_*FC1F_/256), dim3(256), 0, stream, fb1, FC1O);
    hipLaunchKernelGGL(k_fc1m, dim3(32, 16), dim3(256), 0, stream, ABF, WBF, FC1O);
    hipLaunchKernelGGL(k_fc2, dim3(FC2F_), dim3(B_), 0, stream, FC1O, fw2, fb2, out);
}